// Round 2
// baseline (161.479 us; speedup 1.0000x reference)
//
#include <hip/hip_runtime.h>
#include <math.h>

#define NITV 17
#define NCELL (NITV*NITV)        // 289
#define CELLF 6
#define AGG_N (NCELL*CELLF)      // 1734
#define PART_STRIDE 1792
#define NB1 256                  // pass1 blocks

// ws float-offset layout:
// 0     : tE[16] raw thresholds (ehr), 16: tB[16] (bio)
// 32    : rawUe[17*64], 1120: rawVe, 2208: rawUb, 3296: rawVb
// 4384  : SUe[17*68], 5540: SVe, 6696: SUb, 7852: SVb   (padded stride 68)
// 9024  : partials NB1 * PART_STRIDE

__global__ void __launch_bounds__(256) setup_kernel(
    const float* __restrict__ ehr_w, const float* __restrict__ ehr_b,
    const float* __restrict__ bio_w, const float* __restrict__ bio_b,
    const float* __restrict__ bio_qkv_w, const float* __restrict__ bio_qkv_b,
    const float* __restrict__ ehr_qkv_w, const float* __restrict__ ehr_qkv_b,
    const float* __restrict__ attn_in_w, const float* __restrict__ attn_in_b,
    const float* __restrict__ attn_out_w, const float* __restrict__ attn_out_b,
    const float* __restrict__ ab_proj_w, const float* __restrict__ ab_proj_b,
    const float* __restrict__ f1_w, const float* __restrict__ f1_b,
    float* __restrict__ ws)
{
  __shared__ float M[256], mvec[16], P1[256], P2[256], Ae[256], Ab[256];
  __shared__ float uvec[16], vvec[16], cab[16];
  __shared__ float G[1024], Ge[1024], Gb[1024], h0p[64];
  __shared__ float wEx[16], bEx[16], cEx[16], tEx[16];
  __shared__ float wBx[16], bBx[16], cBx[16], tBx[16];
  __shared__ int   rkE[16], rkB[16];
  const int tid = threadIdx.x;

  // Region 1: M = Wo @ Wv(attn V-slice); m = Wo @ bv + bo
  {
    int o = tid >> 4, k = tid & 15;
    double s = 0;
    for (int j = 0; j < 16; ++j)
      s += (double)attn_out_w[o*16+j] * (double)attn_in_w[(32+j)*16+k];
    M[tid] = (float)s;
  }
  if (tid < 16) {
    double s = (double)attn_out_b[tid];
    for (int j = 0; j < 16; ++j)
      s += (double)attn_out_w[tid*16+j] * (double)attn_in_b[32+j];
    mvec[tid] = (float)s;
  }
  __syncthreads();

  // Region 2: P1 = Wp1@M, P2 = Wp2@M ; u = M@bev+m, v = M@bbv+m ; G = F1a + F1b@M
  {
    int o = tid >> 4, i = tid & 15;
    double s1 = 0, s2 = 0;
    for (int t = 0; t < 16; ++t) {
      double mt = (double)M[t*16+i];
      s1 += (double)ab_proj_w[o*32+t]    * mt;
      s2 += (double)ab_proj_w[o*32+16+t] * mt;
    }
    P1[tid] = (float)s1; P2[tid] = (float)s2;
  }
  if (tid < 16) {
    double su = (double)mvec[tid], sv = (double)mvec[tid];
    for (int i = 0; i < 16; ++i) {
      double mt = (double)M[tid*16+i];
      su += mt * (double)ehr_qkv_b[32+i];
      sv += mt * (double)bio_qkv_b[32+i];
    }
    uvec[tid] = (float)su; vvec[tid] = (float)sv;
  }
  for (int idx = tid; idx < 1024; idx += 256) {
    int j = idx >> 4, k = idx & 15;
    double s = (double)f1_w[j*32+k];
    for (int i = 0; i < 16; ++i)
      s += (double)f1_w[j*32+16+i] * (double)M[i*16+k];
    G[idx] = (float)s;
  }
  __syncthreads();

  // Region 3: Ae = P1@Wev, Ab = P2@Wbv ; cab ; thresholds/eff per modality
  {
    int o = tid >> 4, k = tid & 15;
    double s1 = 0, s2 = 0;
    for (int i = 0; i < 16; ++i) {
      s1 += (double)P1[o*16+i] * (double)ehr_qkv_w[(32+i)*16+k];
      s2 += (double)P2[o*16+i] * (double)bio_qkv_w[(32+i)*16+k];
    }
    Ae[tid] = (float)s1; Ab[tid] = (float)s2;
  }
  if (tid < 16) {
    double s = (double)ab_proj_b[tid];
    for (int t = 0; t < 16; ++t) {
      s += (double)ab_proj_w[tid*32+t]    * (double)uvec[t];
      s += (double)ab_proj_w[tid*32+16+t] * (double)vvec[t];
    }
    cab[tid] = (float)s;
  }
  if (tid < 16) {
    float w = ehr_w[tid], b = ehr_b[tid];
    bool z = (w == 0.0f);
    wEx[tid] = z ? 0.f : w;
    bEx[tid] = z ? 0.f : b;
    cEx[tid] = z ? fmaxf(b, 0.f) : 0.f;
    tEx[tid] = z ? __builtin_inff() : (-b / w);
  } else if (tid < 32) {
    int k = tid - 16;
    float w = bio_w[k], b = bio_b[k];
    bool z = (w == 0.0f);
    wBx[k] = z ? 0.f : w;
    bBx[k] = z ? 0.f : b;
    cBx[k] = z ? fmaxf(b, 0.f) : 0.f;
    tBx[k] = z ? __builtin_inff() : (-b / w);
  }
  __syncthreads();

  // Region 4: Ge = G@Ae, Gb = G@Ab ; h0 ; ranks
  for (int idx = tid; idx < 1024; idx += 256) {
    int j = idx >> 4, k = idx & 15;
    double s1 = 0, s2 = 0;
    for (int i = 0; i < 16; ++i) {
      double g = (double)G[j*16+i];
      s1 += g * (double)Ae[i*16+k];
      s2 += g * (double)Ab[i*16+k];
    }
    Ge[idx] = (float)s1; Gb[idx] = (float)s2;
  }
  if (tid < 64) {
    double s = (double)f1_b[tid];
    for (int i = 0; i < 16; ++i) {
      s += (double)G[tid*16+i] * (double)cab[i];
      s += (double)f1_w[tid*32+16+i] * (double)mvec[i];
    }
    h0p[tid] = (float)s;
  }
  if (tid < 16) {
    int r = 0;
    for (int j = 0; j < 16; ++j)
      r += (tEx[j] < tEx[tid]) || (tEx[j] == tEx[tid] && j < tid);
    rkE[tid] = r;
  } else if (tid < 32) {
    int k = tid - 16, r = 0;
    for (int j = 0; j < 16; ++j)
      r += (tBx[j] < tBx[k]) || (tBx[j] == tBx[k] && j < k);
    rkB[k] = r;
  }
  __syncthreads();

  // Region 5: fold constant (zero-slope) units into h0
  if (tid < 64) {
    float s = h0p[tid];
    for (int k = 0; k < 16; ++k)
      s += Ge[tid*16+k]*cEx[k] + Gb[tid*16+k]*cBx[k];
    h0p[tid] = s;
  }
  __syncthreads();

  // Region 6: build raw interval tables; write thresholds
  float* rawUe = ws + 32;
  float* rawVe = ws + 1120;
  float* rawUb = ws + 2208;
  float* rawVb = ws + 3296;
  for (int idx = tid; idx < NITV*64; idx += 256) {
    int i = idx >> 6, j = idx & 63;
    double ue = 0, ve = 0, ub = 0, vb = 0;
    for (int k = 0; k < 16; ++k) {
      bool actE = (wEx[k] > 0.f) ? (rkE[k] < i) : (rkE[k] >= i);
      bool actB = (wBx[k] > 0.f) ? (rkB[k] < i) : (rkB[k] >= i);
      if (actE) { ue += (double)Ge[j*16+k]*(double)wEx[k]; ve += (double)Ge[j*16+k]*(double)bEx[k]; }
      if (actB) { ub += (double)Gb[j*16+k]*(double)wBx[k]; vb += (double)Gb[j*16+k]*(double)bBx[k]; }
    }
    rawUe[idx] = (float)ue;
    rawVe[idx] = (float)(ve + (double)h0p[j]);   // fold all constants into Ve
    rawUb[idx] = (float)ub;
    rawVb[idx] = (float)vb;
  }
  if (tid < 16) { ws[tid] = tEx[tid]; ws[16+tid] = tBx[tid]; }
}

__global__ void __launch_bounds__(256) pass1_kernel(
    const float* __restrict__ x, const float* __restrict__ ws,
    float* __restrict__ partials, int B)
{
  __shared__ float acc[AGG_N];
  const int tid = threadIdx.x;
  for (int i = tid; i < AGG_N; i += 256) acc[i] = 0.f;
  __syncthreads();
  float tE[16], tB[16];
  #pragma unroll
  for (int k = 0; k < 16; ++k) { tE[k] = ws[k]; tB[k] = ws[16+k]; }
  const int stride = gridDim.x * 256;
  for (int i = blockIdx.x*256 + tid; i < B; i += stride) {
    float x0 = x[3*i], x2 = x[3*i+2];
    int iv0 = 0, iv2 = 0;
    #pragma unroll
    for (int k = 0; k < 16; ++k) { iv0 += (tE[k] < x0); iv2 += (tB[k] < x2); }
    float* c = &acc[(iv0*NITV + iv2)*CELLF];
    atomicAdd(c+0, 1.f);
    atomicAdd(c+1, x0);
    atomicAdd(c+2, x2);
    atomicAdd(c+3, x0*x0);
    atomicAdd(c+4, x2*x2);
    atomicAdd(c+5, x0*x2);
  }
  __syncthreads();
  float* out = partials + blockIdx.x*PART_STRIDE;
  for (int i = tid; i < AGG_N; i += 256) out[i] = acc[i];
}

__global__ void __launch_bounds__(256) finalize_kernel(
    const float* __restrict__ partials,
    const float* __restrict__ bn_g, const float* __restrict__ bn_b,
    float* __restrict__ ws, int B)
{
  __shared__ double agg[AGG_N];
  const int tid = threadIdx.x;
  for (int idx = tid; idx < AGG_N; idx += 256) {
    double s = 0;
    for (int b = 0; b < NB1; ++b) s += (double)partials[b*PART_STRIDE + idx];
    agg[idx] = s;
  }
  __syncthreads();
  const float* rawUe = ws + 32;
  const float* rawVe = ws + 1120;
  const float* rawUb = ws + 2208;
  const float* rawVb = ws + 3296;
  float* SUe = ws + 4384;
  float* SVe = ws + 5540;
  float* SUb = ws + 6696;
  float* SVb = ws + 7852;
  if (tid < 64) {
    const int j = tid;
    double ue[NITV], ve[NITV], ub[NITV], vb[NITV];
    #pragma unroll
    for (int i = 0; i < NITV; ++i) {
      ue[i] = rawUe[i*64+j]; ve[i] = rawVe[i*64+j];
      ub[i] = rawUb[i*64+j]; vb[i] = rawVb[i*64+j];
    }
    double sh = 0, sh2 = 0;
    for (int p = 0; p < NITV; ++p) {
      for (int q = 0; q < NITV; ++q) {
        const double* c = &agg[(p*NITV+q)*CELLF];
        double n = c[0], sx0 = c[1], sx2 = c[2], s00 = c[3], s22 = c[4], s02 = c[5];
        double Ue = ue[p], Ve = ve[p], Ub = ub[q], Vb = vb[q];
        sh  += sx0*Ue + n*Ve + sx2*Ub + n*Vb;
        sh2 += s00*Ue*Ue + 2.0*sx0*Ue*Ve + n*Ve*Ve
             + s22*Ub*Ub + 2.0*sx2*Ub*Vb + n*Vb*Vb
             + 2.0*(s02*Ue*Ub + sx0*Ue*Vb + sx2*Ve*Ub + n*Ve*Vb);
      }
    }
    const double invB = 1.0 / (double)B;
    double mu  = sh * invB;
    double var = sh2 * invB - mu*mu;
    double s   = (double)bn_g[j] / sqrt(var + 1e-5);
    double t   = (double)bn_b[j] - mu*s;
    #pragma unroll
    for (int i = 0; i < NITV; ++i) {
      SUe[i*68+j] = (float)(s*ue[i]);
      SVe[i*68+j] = (float)(s*ve[i] + t);
      SUb[i*68+j] = (float)(s*ub[i]);
      SVb[i*68+j] = (float)(s*vb[i]);
    }
  }
  // zero pad columns 64..67 of each scaled table row
  for (int idx = tid; idx < NITV*4; idx += 256) {
    int i = idx % NITV, tbl = idx / NITV;
    float* base = SUe + tbl*1156 + i*68;
    base[64] = 0.f; base[65] = 0.f; base[66] = 0.f; base[67] = 0.f;
  }
}

__global__ void __launch_bounds__(256) pass2_kernel(
    const float* __restrict__ x, const float* __restrict__ ws,
    const float* __restrict__ f2_w, const float* __restrict__ f2_b,
    float* __restrict__ out, int B)
{
  __shared__ __align__(16) float tab[4*1156];
  const int tid = threadIdx.x;
  const float* S = ws + 4384;
  for (int i = tid; i < 4*1156; i += 256) tab[i] = S[i];
  __syncthreads();
  const float* LUe = tab;
  const float* LVe = tab + 1156;
  const float* LUb = tab + 2312;
  const float* LVb = tab + 3468;
  float tE[16], tB[16];
  #pragma unroll
  for (int k = 0; k < 16; ++k) { tE[k] = ws[k]; tB[k] = ws[16+k]; }
  const float b0 = f2_b[0], b1 = f2_b[1], b2 = f2_b[2];
  const int stride = gridDim.x * 256;
  for (int i = blockIdx.x*256 + tid; i < B; i += stride) {
    float x0 = x[3*i], x2 = x[3*i+2];
    int iv0 = 0, iv2 = 0;
    #pragma unroll
    for (int k = 0; k < 16; ++k) { iv0 += (tE[k] < x0); iv2 += (tB[k] < x2); }
    const float4* ue4 = (const float4*)&LUe[iv0*68];
    const float4* ve4 = (const float4*)&LVe[iv0*68];
    const float4* ub4 = (const float4*)&LUb[iv2*68];
    const float4* vb4 = (const float4*)&LVb[iv2*68];
    float a0 = b0, a1 = b1, a2 = b2;
    #pragma unroll
    for (int g = 0; g < 16; ++g) {
      float4 ue = ue4[g], ve = ve4[g], ub = ub4[g], vb = vb4[g];
      const int j = g*4;
      float h, r;
      h = fmaf(x0, ue.x, ve.x) + fmaf(x2, ub.x, vb.x); r = fmaxf(h, 0.f);
      a0 = fmaf(r, f2_w[j+0],     a0); a1 = fmaf(r, f2_w[64+j+0],  a1); a2 = fmaf(r, f2_w[128+j+0], a2);
      h = fmaf(x0, ue.y, ve.y) + fmaf(x2, ub.y, vb.y); r = fmaxf(h, 0.f);
      a0 = fmaf(r, f2_w[j+1],     a0); a1 = fmaf(r, f2_w[64+j+1],  a1); a2 = fmaf(r, f2_w[128+j+1], a2);
      h = fmaf(x0, ue.z, ve.z) + fmaf(x2, ub.z, vb.z); r = fmaxf(h, 0.f);
      a0 = fmaf(r, f2_w[j+2],     a0); a1 = fmaf(r, f2_w[64+j+2],  a1); a2 = fmaf(r, f2_w[128+j+2], a2);
      h = fmaf(x0, ue.w, ve.w) + fmaf(x2, ub.w, vb.w); r = fmaxf(h, 0.f);
      a0 = fmaf(r, f2_w[j+3],     a0); a1 = fmaf(r, f2_w[64+j+3],  a1); a2 = fmaf(r, f2_w[128+j+3], a2);
    }
    out[3*i+0] = a0; out[3*i+1] = a1; out[3*i+2] = a2;
  }
}

extern "C" void kernel_launch(void* const* d_in, const int* in_sizes, int n_in,
                              void* d_out, int out_size, void* d_ws, size_t ws_size,
                              hipStream_t stream) {
  const float* x          = (const float*)d_in[0];
  const float* ehr_w      = (const float*)d_in[1];
  const float* ehr_b      = (const float*)d_in[2];
  const float* bio_w      = (const float*)d_in[5];
  const float* bio_b      = (const float*)d_in[6];
  const float* bio_qkv_w  = (const float*)d_in[7];
  const float* bio_qkv_b  = (const float*)d_in[8];
  const float* ehr_qkv_w  = (const float*)d_in[9];
  const float* ehr_qkv_b  = (const float*)d_in[10];
  const float* attn_in_w  = (const float*)d_in[13];
  const float* attn_in_b  = (const float*)d_in[14];
  const float* attn_out_w = (const float*)d_in[15];
  const float* attn_out_b = (const float*)d_in[16];
  const float* ab_proj_w  = (const float*)d_in[17];
  const float* ab_proj_b  = (const float*)d_in[18];
  const float* f1_w       = (const float*)d_in[19];
  const float* f1_b       = (const float*)d_in[20];
  const float* bn_g       = (const float*)d_in[21];
  const float* bn_b       = (const float*)d_in[22];
  const float* f2_w       = (const float*)d_in[23];
  const float* f2_b       = (const float*)d_in[24];
  float* out = (float*)d_out;
  float* ws  = (float*)d_ws;
  const int B = in_sizes[0] / 3;
  float* partials = ws + 9024;

  setup_kernel<<<1, 256, 0, stream>>>(ehr_w, ehr_b, bio_w, bio_b,
      bio_qkv_w, bio_qkv_b, ehr_qkv_w, ehr_qkv_b,
      attn_in_w, attn_in_b, attn_out_w, attn_out_b,
      ab_proj_w, ab_proj_b, f1_w, f1_b, ws);
  pass1_kernel<<<NB1, 256, 0, stream>>>(x, ws, partials, B);
  finalize_kernel<<<1, 256, 0, stream>>>(partials, bn_g, bn_b, ws, B);
  pass2_kernel<<<1024, 256, 0, stream>>>(x, ws, f2_w, f2_b, out, B);
}

// Round 3
// 98.763 us; speedup vs baseline: 1.6350x; 1.6350x over previous
//
#include <hip/hip_runtime.h>
#include <math.h>

#define NITV 17
#define NCELL (NITV*NITV)        // 289
#define CELLF 6
#define AGG_N (NCELL*CELLF)      // 1734
#define PART_STRIDE 1792
#define NB1 256                  // pass1 blocks
#define NREP 4                   // pass1 LDS accumulator replicas

// ws float-offset layout:
// 0     : tE[16] raw thresholds (ehr), 16: tB[16] (bio)
// 32    : rawUe[17*64], 1120: rawVe, 2208: rawUb, 3296: rawVb
// 4384  : SUe[17*68], 5540: SVe, 6696: SUb, 7852: SVb   (padded stride 68)
// 9024  : partials NB1 * PART_STRIDE  (ends 467776)
// 467776: stage2 [4][PART_STRIDE]     (ends 474944)
#define WS_PART   9024
#define WS_STAGE2 467776

__global__ void __launch_bounds__(256) setup_kernel(
    const float* __restrict__ ehr_w, const float* __restrict__ ehr_b,
    const float* __restrict__ bio_w, const float* __restrict__ bio_b,
    const float* __restrict__ bio_qkv_w, const float* __restrict__ bio_qkv_b,
    const float* __restrict__ ehr_qkv_w, const float* __restrict__ ehr_qkv_b,
    const float* __restrict__ attn_in_w, const float* __restrict__ attn_in_b,
    const float* __restrict__ attn_out_w, const float* __restrict__ attn_out_b,
    const float* __restrict__ ab_proj_w, const float* __restrict__ ab_proj_b,
    const float* __restrict__ f1_w, const float* __restrict__ f1_b,
    float* __restrict__ ws)
{
  __shared__ float M[256], mvec[16], P1[256], P2[256], Ae[256], Ab[256];
  __shared__ float uvec[16], vvec[16], cab[16];
  __shared__ float G[1024], Ge[1024], Gb[1024], h0p[64];
  __shared__ float wEx[16], bEx[16], cEx[16], tEx[16];
  __shared__ float wBx[16], bBx[16], cBx[16], tBx[16];
  __shared__ int   rkE[16], rkB[16];
  const int tid = threadIdx.x;

  // Region 1: M = Wo @ Wv(attn V-slice); m = Wo @ bv + bo
  {
    int o = tid >> 4, k = tid & 15;
    double s = 0;
    for (int j = 0; j < 16; ++j)
      s += (double)attn_out_w[o*16+j] * (double)attn_in_w[(32+j)*16+k];
    M[tid] = (float)s;
  }
  if (tid < 16) {
    double s = (double)attn_out_b[tid];
    for (int j = 0; j < 16; ++j)
      s += (double)attn_out_w[tid*16+j] * (double)attn_in_b[32+j];
    mvec[tid] = (float)s;
  }
  __syncthreads();

  // Region 2: P1 = Wp1@M, P2 = Wp2@M ; u = M@bev+m, v = M@bbv+m ; G = F1a + F1b@M
  {
    int o = tid >> 4, i = tid & 15;
    double s1 = 0, s2 = 0;
    for (int t = 0; t < 16; ++t) {
      double mt = (double)M[t*16+i];
      s1 += (double)ab_proj_w[o*32+t]    * mt;
      s2 += (double)ab_proj_w[o*32+16+t] * mt;
    }
    P1[tid] = (float)s1; P2[tid] = (float)s2;
  }
  if (tid < 16) {
    double su = (double)mvec[tid], sv = (double)mvec[tid];
    for (int i = 0; i < 16; ++i) {
      double mt = (double)M[tid*16+i];
      su += mt * (double)ehr_qkv_b[32+i];
      sv += mt * (double)bio_qkv_b[32+i];
    }
    uvec[tid] = (float)su; vvec[tid] = (float)sv;
  }
  for (int idx = tid; idx < 1024; idx += 256) {
    int j = idx >> 4, k = idx & 15;
    double s = (double)f1_w[j*32+k];
    for (int i = 0; i < 16; ++i)
      s += (double)f1_w[j*32+16+i] * (double)M[i*16+k];
    G[idx] = (float)s;
  }
  __syncthreads();

  // Region 3: Ae = P1@Wev, Ab = P2@Wbv ; cab ; thresholds/eff per modality
  {
    int o = tid >> 4, k = tid & 15;
    double s1 = 0, s2 = 0;
    for (int i = 0; i < 16; ++i) {
      s1 += (double)P1[o*16+i] * (double)ehr_qkv_w[(32+i)*16+k];
      s2 += (double)P2[o*16+i] * (double)bio_qkv_w[(32+i)*16+k];
    }
    Ae[tid] = (float)s1; Ab[tid] = (float)s2;
  }
  if (tid < 16) {
    double s = (double)ab_proj_b[tid];
    for (int t = 0; t < 16; ++t) {
      s += (double)ab_proj_w[tid*32+t]    * (double)uvec[t];
      s += (double)ab_proj_w[tid*32+16+t] * (double)vvec[t];
    }
    cab[tid] = (float)s;
  }
  if (tid < 16) {
    float w = ehr_w[tid], b = ehr_b[tid];
    bool z = (w == 0.0f);
    wEx[tid] = z ? 0.f : w;
    bEx[tid] = z ? 0.f : b;
    cEx[tid] = z ? fmaxf(b, 0.f) : 0.f;
    tEx[tid] = z ? __builtin_inff() : (-b / w);
  } else if (tid < 32) {
    int k = tid - 16;
    float w = bio_w[k], b = bio_b[k];
    bool z = (w == 0.0f);
    wBx[k] = z ? 0.f : w;
    bBx[k] = z ? 0.f : b;
    cBx[k] = z ? fmaxf(b, 0.f) : 0.f;
    tBx[k] = z ? __builtin_inff() : (-b / w);
  }
  __syncthreads();

  // Region 4: Ge = G@Ae, Gb = G@Ab ; h0 ; ranks
  for (int idx = tid; idx < 1024; idx += 256) {
    int j = idx >> 4, k = idx & 15;
    double s1 = 0, s2 = 0;
    for (int i = 0; i < 16; ++i) {
      double g = (double)G[j*16+i];
      s1 += g * (double)Ae[i*16+k];
      s2 += g * (double)Ab[i*16+k];
    }
    Ge[idx] = (float)s1; Gb[idx] = (float)s2;
  }
  if (tid < 64) {
    double s = (double)f1_b[tid];
    for (int i = 0; i < 16; ++i) {
      s += (double)G[tid*16+i] * (double)cab[i];
      s += (double)f1_w[tid*32+16+i] * (double)mvec[i];
    }
    h0p[tid] = (float)s;
  }
  if (tid < 16) {
    int r = 0;
    for (int j = 0; j < 16; ++j)
      r += (tEx[j] < tEx[tid]) || (tEx[j] == tEx[tid] && j < tid);
    rkE[tid] = r;
  } else if (tid < 32) {
    int k = tid - 16, r = 0;
    for (int j = 0; j < 16; ++j)
      r += (tBx[j] < tBx[k]) || (tBx[j] == tBx[k] && j < k);
    rkB[k] = r;
  }
  __syncthreads();

  // Region 5: fold constant (zero-slope) units into h0
  if (tid < 64) {
    float s = h0p[tid];
    for (int k = 0; k < 16; ++k)
      s += Ge[tid*16+k]*cEx[k] + Gb[tid*16+k]*cBx[k];
    h0p[tid] = s;
  }
  __syncthreads();

  // Region 6: build raw interval tables; write thresholds
  float* rawUe = ws + 32;
  float* rawVe = ws + 1120;
  float* rawUb = ws + 2208;
  float* rawVb = ws + 3296;
  for (int idx = tid; idx < NITV*64; idx += 256) {
    int i = idx >> 6, j = idx & 63;
    double ue = 0, ve = 0, ub = 0, vb = 0;
    for (int k = 0; k < 16; ++k) {
      bool actE = (wEx[k] > 0.f) ? (rkE[k] < i) : (rkE[k] >= i);
      bool actB = (wBx[k] > 0.f) ? (rkB[k] < i) : (rkB[k] >= i);
      if (actE) { ue += (double)Ge[j*16+k]*(double)wEx[k]; ve += (double)Ge[j*16+k]*(double)bEx[k]; }
      if (actB) { ub += (double)Gb[j*16+k]*(double)wBx[k]; vb += (double)Gb[j*16+k]*(double)bBx[k]; }
    }
    rawUe[idx] = (float)ue;
    rawVe[idx] = (float)(ve + (double)h0p[j]);   // fold all constants into Ve
    rawUb[idx] = (float)ub;
    rawVb[idx] = (float)vb;
  }
  if (tid < 16) { ws[tid] = tEx[tid]; ws[16+tid] = tBx[tid]; }
}

__global__ void __launch_bounds__(256) pass1_kernel(
    const float* __restrict__ x, const float* __restrict__ ws,
    float* __restrict__ partials, int B)
{
  __shared__ float acc[NREP][AGG_N];   // 4 x 1734 x 4B = 27.7 KB
  const int tid = threadIdx.x;
  for (int i = tid; i < NREP*AGG_N; i += 256) (&acc[0][0])[i] = 0.f;
  __syncthreads();
  float tE[16], tB[16];
  #pragma unroll
  for (int k = 0; k < 16; ++k) { tE[k] = ws[k]; tB[k] = ws[16+k]; }
  const int rep = tid & (NREP-1);
  const int stride = gridDim.x * 256;
  for (int i = blockIdx.x*256 + tid; i < B; i += stride) {
    float x0 = x[3*i], x2 = x[3*i+2];
    int iv0 = 0, iv2 = 0;
    #pragma unroll
    for (int k = 0; k < 16; ++k) { iv0 += (tE[k] < x0); iv2 += (tB[k] < x2); }
    float* c = &acc[rep][(iv0*NITV + iv2)*CELLF];
    atomicAdd(c+0, 1.f);
    atomicAdd(c+1, x0);
    atomicAdd(c+2, x2);
    atomicAdd(c+3, x0*x0);
    atomicAdd(c+4, x2*x2);
    atomicAdd(c+5, x0*x2);
  }
  __syncthreads();
  float* out = partials + blockIdx.x*PART_STRIDE;
  for (int i = tid; i < AGG_N; i += 256)
    out[i] = (acc[0][i] + acc[1][i]) + (acc[2][i] + acc[3][i]);
}

// 28 blocks: c = blockIdx%7 (idx chunk of 256), g = blockIdx/7 (b-group of 64).
// stage2[g*PART_STRIDE + idx] = sum over 64 pass1-blocks of partials.
__global__ void __launch_bounds__(256) reduce_kernel(
    const float* __restrict__ partials, float* __restrict__ stage2)
{
  const int c = blockIdx.x % 7, g = blockIdx.x / 7;
  const int idx = c*256 + threadIdx.x;
  if (idx >= AGG_N) return;
  const float* p = partials + (size_t)g*64*PART_STRIDE + idx;
  float s = 0.f;
  #pragma unroll 8
  for (int b = 0; b < 64; ++b) s += p[b*PART_STRIDE];
  stage2[g*PART_STRIDE + idx] = s;
}

__global__ void __launch_bounds__(256) finalize_kernel(
    const float* __restrict__ stage2,
    const float* __restrict__ bn_g, const float* __restrict__ bn_b,
    float* __restrict__ ws, int B)
{
  __shared__ double agg[AGG_N];                 // 13.9 KB
  __shared__ double shp[4][64], sh2p[4][64];    // 4 KB
  const int tid = threadIdx.x;
  for (int idx = tid; idx < AGG_N; idx += 256) {
    float s = (stage2[idx] + stage2[PART_STRIDE + idx])
            + (stage2[2*PART_STRIDE + idx] + stage2[3*PART_STRIDE + idx]);
    agg[idx] = (double)s;
  }
  __syncthreads();
  const float* rawUe = ws + 32;
  const float* rawVe = ws + 1120;
  const float* rawUb = ws + 2208;
  const float* rawVb = ws + 3296;
  float* SUe = ws + 4384;
  float* SVe = ws + 5540;
  float* SUb = ws + 6696;
  float* SVb = ws + 7852;

  // Parallel cell loop: 4 wave-groups each take a stripe of p.
  {
    const int j = tid & 63, pg = tid >> 6;
    double ub[NITV], vb[NITV];
    #pragma unroll
    for (int q = 0; q < NITV; ++q) { ub[q] = rawUb[q*64+j]; vb[q] = rawVb[q*64+j]; }
    double sh = 0, sh2 = 0;
    for (int p = pg; p < NITV; p += 4) {
      const double Ue = rawUe[p*64+j], Ve = rawVe[p*64+j];
      for (int q = 0; q < NITV; ++q) {
        const double* c = &agg[(p*NITV+q)*CELLF];
        double n = c[0], sx0 = c[1], sx2 = c[2], s00 = c[3], s22 = c[4], s02 = c[5];
        double Ub = ub[q], Vb = vb[q];
        sh  += sx0*Ue + n*Ve + sx2*Ub + n*Vb;
        sh2 += s00*Ue*Ue + 2.0*sx0*Ue*Ve + n*Ve*Ve
             + s22*Ub*Ub + 2.0*sx2*Ub*Vb + n*Vb*Vb
             + 2.0*(s02*Ue*Ub + sx0*Ue*Vb + sx2*Ve*Ub + n*Ve*Vb);
      }
    }
    shp[pg][j] = sh; sh2p[pg][j] = sh2;
  }
  __syncthreads();
  if (tid < 64) {
    const int j = tid;
    double sh  = (shp[0][j]  + shp[1][j])  + (shp[2][j]  + shp[3][j]);
    double sh2 = (sh2p[0][j] + sh2p[1][j]) + (sh2p[2][j] + sh2p[3][j]);
    const double invB = 1.0 / (double)B;
    double mu  = sh * invB;
    double var = sh2 * invB - mu*mu;
    double s   = (double)bn_g[j] / sqrt(var + 1e-5);
    double t   = (double)bn_b[j] - mu*s;
    #pragma unroll
    for (int i = 0; i < NITV; ++i) {
      SUe[i*68+j] = (float)(s*(double)rawUe[i*64+j]);
      SVe[i*68+j] = (float)(s*(double)rawVe[i*64+j] + t);
      SUb[i*68+j] = (float)(s*(double)rawUb[i*64+j]);
      SVb[i*68+j] = (float)(s*(double)rawVb[i*64+j]);
    }
  }
  // zero pad columns 64..67 of each scaled table row
  for (int idx = tid; idx < NITV*4; idx += 256) {
    int i = idx % NITV, tbl = idx / NITV;
    float* base = SUe + tbl*1156 + i*68;
    base[64] = 0.f; base[65] = 0.f; base[66] = 0.f; base[67] = 0.f;
  }
}

__global__ void __launch_bounds__(256) pass2_kernel(
    const float* __restrict__ x, const float* __restrict__ ws,
    const float* __restrict__ f2_w, const float* __restrict__ f2_b,
    float* __restrict__ out, int B)
{
  __shared__ __align__(16) float tab[4*1156];
  const int tid = threadIdx.x;
  const float* S = ws + 4384;
  for (int i = tid; i < 4*1156; i += 256) tab[i] = S[i];
  __syncthreads();
  const float* LUe = tab;
  const float* LVe = tab + 1156;
  const float* LUb = tab + 2312;
  const float* LVb = tab + 3468;
  float tE[16], tB[16];
  #pragma unroll
  for (int k = 0; k < 16; ++k) { tE[k] = ws[k]; tB[k] = ws[16+k]; }
  const float b0 = f2_b[0], b1 = f2_b[1], b2 = f2_b[2];
  const int stride = gridDim.x * 256;
  for (int i = blockIdx.x*256 + tid; i < B; i += stride) {
    float x0 = x[3*i], x2 = x[3*i+2];
    int iv0 = 0, iv2 = 0;
    #pragma unroll
    for (int k = 0; k < 16; ++k) { iv0 += (tE[k] < x0); iv2 += (tB[k] < x2); }
    const float4* ue4 = (const float4*)&LUe[iv0*68];
    const float4* ve4 = (const float4*)&LVe[iv0*68];
    const float4* ub4 = (const float4*)&LUb[iv2*68];
    const float4* vb4 = (const float4*)&LVb[iv2*68];
    float a0 = b0, a1 = b1, a2 = b2;
    #pragma unroll
    for (int g = 0; g < 16; ++g) {
      float4 ue = ue4[g], ve = ve4[g], ub = ub4[g], vb = vb4[g];
      const int j = g*4;
      float h, r;
      h = fmaf(x0, ue.x, ve.x) + fmaf(x2, ub.x, vb.x); r = fmaxf(h, 0.f);
      a0 = fmaf(r, f2_w[j+0],     a0); a1 = fmaf(r, f2_w[64+j+0],  a1); a2 = fmaf(r, f2_w[128+j+0], a2);
      h = fmaf(x0, ue.y, ve.y) + fmaf(x2, ub.y, vb.y); r = fmaxf(h, 0.f);
      a0 = fmaf(r, f2_w[j+1],     a0); a1 = fmaf(r, f2_w[64+j+1],  a1); a2 = fmaf(r, f2_w[128+j+1], a2);
      h = fmaf(x0, ue.z, ve.z) + fmaf(x2, ub.z, vb.z); r = fmaxf(h, 0.f);
      a0 = fmaf(r, f2_w[j+2],     a0); a1 = fmaf(r, f2_w[64+j+2],  a1); a2 = fmaf(r, f2_w[128+j+2], a2);
      h = fmaf(x0, ue.w, ve.w) + fmaf(x2, ub.w, vb.w); r = fmaxf(h, 0.f);
      a0 = fmaf(r, f2_w[j+3],     a0); a1 = fmaf(r, f2_w[64+j+3],  a1); a2 = fmaf(r, f2_w[128+j+3], a2);
    }
    out[3*i+0] = a0; out[3*i+1] = a1; out[3*i+2] = a2;
  }
}

extern "C" void kernel_launch(void* const* d_in, const int* in_sizes, int n_in,
                              void* d_out, int out_size, void* d_ws, size_t ws_size,
                              hipStream_t stream) {
  const float* x          = (const float*)d_in[0];
  const float* ehr_w      = (const float*)d_in[1];
  const float* ehr_b      = (const float*)d_in[2];
  const float* bio_w      = (const float*)d_in[5];
  const float* bio_b      = (const float*)d_in[6];
  const float* bio_qkv_w  = (const float*)d_in[7];
  const float* bio_qkv_b  = (const float*)d_in[8];
  const float* ehr_qkv_w  = (const float*)d_in[9];
  const float* ehr_qkv_b  = (const float*)d_in[10];
  const float* attn_in_w  = (const float*)d_in[13];
  const float* attn_in_b  = (const float*)d_in[14];
  const float* attn_out_w = (const float*)d_in[15];
  const float* attn_out_b = (const float*)d_in[16];
  const float* ab_proj_w  = (const float*)d_in[17];
  const float* ab_proj_b  = (const float*)d_in[18];
  const float* f1_w       = (const float*)d_in[19];
  const float* f1_b       = (const float*)d_in[20];
  const float* bn_g       = (const float*)d_in[21];
  const float* bn_b       = (const float*)d_in[22];
  const float* f2_w       = (const float*)d_in[23];
  const float* f2_b       = (const float*)d_in[24];
  float* out = (float*)d_out;
  float* ws  = (float*)d_ws;
  const int B = in_sizes[0] / 3;
  float* partials = ws + WS_PART;
  float* stage2   = ws + WS_STAGE2;

  setup_kernel<<<1, 256, 0, stream>>>(ehr_w, ehr_b, bio_w, bio_b,
      bio_qkv_w, bio_qkv_b, ehr_qkv_w, ehr_qkv_b,
      attn_in_w, attn_in_b, attn_out_w, attn_out_b,
      ab_proj_w, ab_proj_b, f1_w, f1_b, ws);
  pass1_kernel<<<NB1, 256, 0, stream>>>(x, ws, partials, B);
  reduce_kernel<<<28, 256, 0, stream>>>(partials, stage2);
  finalize_kernel<<<1, 256, 0, stream>>>(stage2, bn_g, bn_b, ws, B);
  pass2_kernel<<<1024, 256, 0, stream>>>(x, ws, f2_w, f2_b, out, B);
}